// Round 16
// baseline (320.408 us; speedup 1.0000x reference)
//
#include <hip/hip_runtime.h>
#include <hip/hip_bf16.h>

#define NN 50000
#define EE 200000
#define HH 8
#define CC 256
#define IND 256
#define HC 2048
#define NEG 0.2f
#define EPSV 1e-16f

typedef __attribute__((ext_vector_type(8))) short short8;
typedef __attribute__((ext_vector_type(4))) float f32x4;

__device__ __forceinline__ float b2f(unsigned short u) {
  return __uint_as_float(((unsigned)u) << 16);
}
__device__ __forceinline__ unsigned short f2b(float f) {
  unsigned u = __float_as_uint(f);
  unsigned r = (u + 0x7FFFu + ((u >> 16) & 1u)) >> 16;
  return (unsigned short)r;
}

// ---------------- build Wstack^T: wt2[cout][kk] = W[kk&255][(kk>>8)*256+cout]*0.125 ----------------
__global__ __launch_bounds__(1024) void k_wt2(const float* __restrict__ W,
                                              unsigned short* __restrict__ wt2) {
  __shared__ float tile[32][33];
  int kk0 = blockIdx.x * 32;   // over 2048 (h*256+k)
  int c0 = blockIdx.y * 32;    // over 256 couts
  int tx = threadIdx.x & 31, ty = threadIdx.x >> 5;
  int h = kk0 >> 8;
  int k = (kk0 & 255) + ty;
  tile[ty][tx] = W[(size_t)k * HC + h * 256 + c0 + tx] * 0.125f;
  __syncthreads();
  wt2[(size_t)(c0 + ty) * HC + kk0 + tx] = f2b(tile[tx][ty]);
}

// ---------------- fold W against att vectors: wfold[in][h] ----------------
__global__ __launch_bounds__(256) void k_wfold(const float* __restrict__ W,
                                               const float* __restrict__ att_s,
                                               const float* __restrict__ att_d,
                                               float* __restrict__ wsrc,
                                               float* __restrict__ wdst) {
  int in = blockIdx.x;
  int t = threadIdx.x;
  int h = t >> 5;
  int c0 = (t & 31) * 8;
  float ps = 0.f, pd = 0.f;
#pragma unroll
  for (int j = 0; j < 8; ++j) {
    float wv = W[(size_t)in * HC + h * 256 + c0 + j];
    ps += wv * att_s[h * 256 + c0 + j];
    pd += wv * att_d[h * 256 + c0 + j];
  }
#pragma unroll
  for (int o = 16; o >= 1; o >>= 1) {
    ps += __shfl_down(ps, o, 32);
    pd += __shfl_down(pd, o, 32);
  }
  if ((t & 31) == 0) {
    wsrc[in * HH + h] = ps;
    wdst[in * HH + h] = pd;
  }
}

// ---------------- fused: bf16 convert of x + per-node logits + edge histogram ----------------
__global__ __launch_bounds__(256) void k_alog2c(const float* __restrict__ x,
                                                const float* __restrict__ wsrc,
                                                const float* __restrict__ wdst,
                                                const int* __restrict__ dstn,
                                                unsigned short* __restrict__ xb,
                                                float* __restrict__ a_src,
                                                float* __restrict__ a_dst,
                                                int* __restrict__ deg) {
  int gid = blockIdx.x * 256 + threadIdx.x;
  if (gid < EE) atomicAdd(&deg[dstn[gid]], 1);

  const int l = threadIdx.x & 63;
  const int gwave = (blockIdx.x * 256 + threadIdx.x) >> 6;
  const int nwaves = (gridDim.x * 256) >> 6;
  float ws_[4][8], wd_[4][8];
#pragma unroll
  for (int j = 0; j < 4; ++j) {
#pragma unroll
    for (int h = 0; h < 8; ++h) {
      ws_[j][h] = wsrc[(l * 4 + j) * HH + h];
      wd_[j][h] = wdst[(l * 4 + j) * HH + h];
    }
  }
  for (int n = gwave; n < NN; n += nwaves) {
    float4 xv = *(const float4*)(x + (size_t)n * IND + l * 4);
    float xa[4] = {xv.x, xv.y, xv.z, xv.w};
    ushort4 o = make_ushort4(f2b(xv.x), f2b(xv.y), f2b(xv.z), f2b(xv.w));
    *(ushort4*)(xb + (size_t)n * IND + l * 4) = o;
    float as[8] = {}, ad[8] = {};
#pragma unroll
    for (int j = 0; j < 4; ++j)
#pragma unroll
      for (int h = 0; h < 8; ++h) {
        as[h] += xa[j] * ws_[j][h];
        ad[h] += xa[j] * wd_[j][h];
      }
#pragma unroll
    for (int o2 = 32; o2 >= 1; o2 >>= 1) {
#pragma unroll
      for (int h = 0; h < 8; ++h) {
        as[h] += __shfl_down(as[h], o2);
        ad[h] += __shfl_down(ad[h], o2);
      }
    }
    if (l == 0) {
#pragma unroll
      for (int h = 0; h < 8; ++h) {
        a_src[n * HH + h] = as[h];
        a_dst[n * HH + h] = ad[h];
      }
    }
  }
}

// ---------------- CSR build ----------------
__global__ __launch_bounds__(1024) void k_scanA(const int* __restrict__ deg,
                                                int* __restrict__ incl, int* __restrict__ bsum) {
  __shared__ int s[1024];
  int tid = threadIdx.x;
  int i = blockIdx.x * 1024 + tid;
  s[tid] = (i < NN) ? deg[i] : 0;
  __syncthreads();
  for (int o = 1; o < 1024; o <<= 1) {
    int add = (tid >= o) ? s[tid - o] : 0;
    __syncthreads();
    s[tid] += add;
    __syncthreads();
  }
  if (i < NN) incl[i] = s[tid];
  if (tid == 1023) bsum[blockIdx.x] = s[1023];
}

// scanC with fused block-sum prefix (wave 0 scans bsum, <=64 blocks)
__global__ __launch_bounds__(1024) void k_scanC(const int* __restrict__ deg, const int* __restrict__ incl,
                                                const int* __restrict__ bsum, int* __restrict__ row_start,
                                                int* __restrict__ cursor) {
  __shared__ int base_s;
  int tid = threadIdx.x;
  if (tid < 64) {
    int nb = gridDim.x;
    int v = (tid < nb) ? bsum[tid] : 0;
    int p = v;
#pragma unroll
    for (int o = 1; o < 64; o <<= 1) {
      int tt = __shfl_up(p, o, 64);
      if (tid >= o) p += tt;
    }
    if (tid == (int)blockIdx.x) base_s = p - v;   // exclusive prefix for this block
  }
  __syncthreads();
  int i = blockIdx.x * 1024 + tid;
  if (i < NN) {
    int ex = base_s + incl[i] - deg[i];
    row_start[i] = ex;
    cursor[i] = ex;
  }
  if (i == 0) row_start[NN] = EE;
}

__global__ void k_scatter(const int* __restrict__ srcn, const int* __restrict__ dstn,
                          int* __restrict__ cursor, int* __restrict__ csr_src) {
  int e = blockIdx.x * 256 + threadIdx.x;
  if (e < EE) {
    int d = dstn[e];
    int p = atomicAdd(&cursor[d], 1);
    csr_src[p] = srcn[e];
  }
}

// ---------------- fused softmax + aggregate in x-space: SINGLE PASS ----------------
__global__ __launch_bounds__(256) void k_aggxf(const unsigned short* __restrict__ xb,
                                               const float* __restrict__ a_src,
                                               const float* __restrict__ a_dst,
                                               const int* __restrict__ row_start,
                                               const int* __restrict__ csr_src,
                                               unsigned short* __restrict__ y) {
  __shared__ float w_s[4][8][8];    // [wave][edge-in-chunk][head] exp weights
  __shared__ float inv_s[4][8];     // [wave][head] 1/denominator
  const int l = threadIdx.x & 63;
  const int wv = threadIdx.x >> 6;
  const int n = blockIdx.x * 4 + wv;
  if (n >= NN) return;
  const int start = row_start[n];
  const int D = row_start[n + 1] - start;
  unsigned short* yp = y + (size_t)n * HC + l * 4;
  if (D == 0) {
    ushort4 z = make_ushort4(0, 0, 0, 0);
#pragma unroll
    for (int h = 0; h < 8; ++h) *(ushort4*)(yp + h * 256) = z;
    return;
  }
  const int h = l & 7;
  const int e8 = l >> 3;
  const float adst = a_dst[n * HH + h];

  float ssum = 0.f;
  float acc[8][4] = {};
  for (int base = 0; base < D; base += 8) {
    int nch = min(8, D - base);
    int e = base + e8;
    int s = 0;
    float we = 0.f;
    if (e < D) {
      s = csr_src[start + e];
      float xv = a_src[s * HH + h] + adst;
      float lg = (xv > 0.f) ? xv : NEG * xv;
      we = __expf(fminf(lg, 60.f));
      ssum += we;
    }
    w_s[wv][e8][h] = we;   // wave-synchronous LDS
    for (int ee = 0; ee < nch; ++ee) {
      int se = __shfl(s, ee * 8, 64);
      f32x4 a0 = *(const f32x4*)&w_s[wv][ee][0];   // broadcast read
      f32x4 a1 = *(const f32x4*)&w_s[wv][ee][4];
      ushort4 v = *(const ushort4*)(xb + (size_t)se * IND + l * 4);
      float x0 = b2f(v.x), x1 = b2f(v.y), x2 = b2f(v.z), x3 = b2f(v.w);
#pragma unroll
      for (int hh = 0; hh < 8; ++hh) {
        float a = (hh < 4) ? a0[hh] : a1[hh - 4];
        acc[hh][0] += a * x0;
        acc[hh][1] += a * x1;
        acc[hh][2] += a * x2;
        acc[hh][3] += a * x3;
      }
    }
  }
#pragma unroll
  for (int mask = 8; mask < 64; mask <<= 1) ssum += __shfl_xor(ssum, mask, 64);
  if (e8 == 0) inv_s[wv][h] = 1.f / (ssum + EPSV);
  f32x4 i0 = *(const f32x4*)&inv_s[wv][0];
  f32x4 i1 = *(const f32x4*)&inv_s[wv][4];
#pragma unroll
  for (int hh = 0; hh < 8; ++hh) {
    float iv = (hh < 4) ? i0[hh] : i1[hh - 4];
    ushort4 o = make_ushort4(f2b(acc[hh][0] * iv), f2b(acc[hh][1] * iv),
                             f2b(acc[hh][2] * iv), f2b(acc[hh][3] * iv));
    *(ushort4*)(yp + hh * 256) = o;
  }
}

// ---------------- GEMM2: out += y[N][khalf-slice] @ wt2^T (+bias on half 0) ----------------
// R10-proven inner loop (BM=128, BN=256, BK=64, 8 waves, single 48KB LDS, 2-barrier),
// K-SPLIT 2 via blockIdx.y: 16 K-steps per block, grid 391x2 = 782 blocks -> 3.05
// rounds, 3 blocks/CU co-resident (144KB LDS) -> deeper stage/compute overlap and
// smaller idle tail. Epilogue: f32 atomicAdd into pre-zeroed out (2 commutative
// adds per element -> deterministic); bias folded into the khalf==0 contribution.
__global__ __launch_bounds__(512) void k_gemm2(const unsigned short* __restrict__ y,
                                               const unsigned short* __restrict__ wt2,
                                               const float* __restrict__ bias,
                                               float* __restrict__ out) {
  __shared__ unsigned short As[128 * 64];   // 16KB
  __shared__ unsigned short Bs[256 * 64];   // 32KB
  const int t = threadIdx.x;
  const int lane = t & 63;
  const int w = t >> 6;          // 0..7
  const int wr = w >> 2;         // 0..1  (row half)
  const int wc = w & 3;          // 0..3  (col quarter)
  const int l16 = lane & 15;
  const int lq = lane >> 4;
  const int m0 = blockIdx.x * 128;
  const int kbase = blockIdx.y * 1024;

  f32x4 acc[4][4] = {};

  const int so = t * 16;   // byte offset within an 8KB issue-slice

  for (int ks = 0; ks < 16; ++ks) {
    const int k0 = kbase + ks * 64;
#pragma unroll
    for (int i = 0; i < 2; ++i) {
      int o = i * 8192 + so;
      int row = o >> 7;
      int cg = ((o >> 4) & 7) ^ (row & 7);
      const unsigned short* srcA = y + (size_t)(m0 + row) * HC + k0 + cg * 8;
      __builtin_amdgcn_global_load_lds(
          (const __attribute__((address_space(1))) void*)srcA,
          (__attribute__((address_space(3))) void*)((char*)As + o), 16, 0, 0);
    }
#pragma unroll
    for (int i = 0; i < 4; ++i) {
      int o = i * 8192 + so;
      int row = o >> 7;
      int cg = ((o >> 4) & 7) ^ (row & 7);
      const unsigned short* srcB = wt2 + (size_t)row * HC + k0 + cg * 8;
      __builtin_amdgcn_global_load_lds(
          (const __attribute__((address_space(1))) void*)srcB,
          (__attribute__((address_space(3))) void*)((char*)Bs + o), 16, 0, 0);
    }
    __syncthreads();
#pragma unroll
    for (int kk = 0; kk < 2; ++kk) {
      short8 af[4], bf[4];
#pragma unroll
      for (int m = 0; m < 4; ++m) {
        int row = wr * 64 + m * 16 + l16;
        int byte = row * 128 + (((kk * 4 + lq) ^ (row & 7)) << 4);
        af[m] = *(const short8*)((const char*)As + byte);
      }
#pragma unroll
      for (int n = 0; n < 4; ++n) {
        int row = wc * 64 + n * 16 + l16;
        int byte = row * 128 + (((kk * 4 + lq) ^ (row & 7)) << 4);
        bf[n] = *(const short8*)((const char*)Bs + byte);
      }
      __builtin_amdgcn_s_setprio(1);
#pragma unroll
      for (int m = 0; m < 4; ++m)
#pragma unroll
        for (int n = 0; n < 4; ++n)
          acc[m][n] = __builtin_amdgcn_mfma_f32_16x16x32_bf16(af[m], bf[n], acc[m][n], 0, 0, 0);
      __builtin_amdgcn_s_setprio(0);
    }
    __syncthreads();
  }

  const int r0 = lq * 4;
#pragma unroll
  for (int n = 0; n < 4; ++n) {
    int gcol = wc * 64 + n * 16 + l16;
    float bv = (blockIdx.y == 0) ? bias[gcol] : 0.f;
#pragma unroll
    for (int m = 0; m < 4; ++m) {
#pragma unroll
      for (int r = 0; r < 4; ++r) {
        int grow = m0 + wr * 64 + m * 16 + r0 + r;
        if (grow < NN) atomicAdd(&out[(size_t)grow * CC + gcol], acc[m][n][r] + bv);
      }
    }
  }
}

// ---------------- launch ----------------
extern "C" void kernel_launch(void* const* d_in, const int* in_sizes, int n_in,
                              void* d_out, int out_size, void* d_ws, size_t ws_size,
                              hipStream_t stream) {
  (void)in_sizes; (void)n_in; (void)out_size; (void)ws_size;
  const float* x = (const float*)d_in[0];
  const int* ei = (const int*)d_in[1];
  const float* W = (const float*)d_in[2];
  const float* att_s = (const float*)d_in[3];
  const float* att_d = (const float*)d_in[4];
  const float* bias = (const float*)d_in[5];
  float* out = (float*)d_out;
  const int* srcp = ei;
  const int* dstp = ei + EE;

  char* ws = (char*)d_ws;
  size_t off = 0;
  auto alloc = [&](size_t bytes) {
    void* p = ws + off;
    off = (off + bytes + 255) & ~(size_t)255;
    return p;
  };
  unsigned short* y = (unsigned short*)alloc((size_t)NN * HC * 2);
  unsigned short* xb = (unsigned short*)alloc((size_t)NN * IND * 2);  // also OOB pad for y rows >= NN
  unsigned short* wt2 = (unsigned short*)alloc((size_t)HC * IND * 2);
  float* wsrc = (float*)alloc((size_t)IND * HH * 4);
  float* wdst = (float*)alloc((size_t)IND * HH * 4);
  float* a_src = (float*)alloc((size_t)NN * HH * 4);
  float* a_dst = (float*)alloc((size_t)NN * HH * 4);
  int* deg = (int*)alloc((size_t)NN * 4);
  int* incl = (int*)alloc((size_t)NN * 4);
  int* row_start = (int*)alloc((size_t)(NN + 1) * 4);
  int* cursor = (int*)alloc((size_t)NN * 4);
  int* csr_src = (int*)alloc((size_t)EE * 4);
  int* bsum = (int*)alloc(256);

  hipMemsetAsync(deg, 0, (size_t)NN * 4, stream);
  hipMemsetAsync(out, 0, (size_t)NN * CC * 4, stream);

  k_wt2<<<dim3(HC / 32, CC / 32), 1024, 0, stream>>>(W, wt2);
  k_wfold<<<IND, 256, 0, stream>>>(W, att_s, att_d, wsrc, wdst);
  k_alog2c<<<832, 256, 0, stream>>>(x, wsrc, wdst, dstp, xb, a_src, a_dst, deg);
  int nb = (NN + 1023) / 1024;
  k_scanA<<<nb, 1024, 0, stream>>>(deg, incl, bsum);
  k_scanC<<<nb, 1024, 0, stream>>>(deg, incl, bsum, row_start, cursor);
  k_scatter<<<(EE + 255) / 256, 256, 0, stream>>>(srcp, dstp, cursor, csr_src);
  k_aggxf<<<(NN + 3) / 4, 256, 0, stream>>>(xb, a_src, a_dst, row_start, csr_src, y);
  k_gemm2<<<dim3((NN + 127) / 128, 2), 512, 0, stream>>>(y, wt2, bias, out);
}

// Round 17
// 319.589 us; speedup vs baseline: 1.0026x; 1.0026x over previous
//
#include <hip/hip_runtime.h>
#include <hip/hip_bf16.h>

#define NN 50000
#define EE 200000
#define HH 8
#define CC 256
#define IND 256
#define HC 2048
#define NEG 0.2f
#define EPSV 1e-16f

typedef __attribute__((ext_vector_type(8))) short short8;
typedef __attribute__((ext_vector_type(4))) float f32x4;

__device__ __forceinline__ float b2f(unsigned short u) {
  return __uint_as_float(((unsigned)u) << 16);
}
__device__ __forceinline__ unsigned short f2b(float f) {
  unsigned u = __float_as_uint(f);
  unsigned r = (u + 0x7FFFu + ((u >> 16) & 1u)) >> 16;
  return (unsigned short)r;
}

// ---------------- build Wstack^T: wt2[cout][kk] = W[kk&255][(kk>>8)*256+cout]*0.125 ----------------
__global__ __launch_bounds__(1024) void k_wt2(const float* __restrict__ W,
                                              unsigned short* __restrict__ wt2) {
  __shared__ float tile[32][33];
  int kk0 = blockIdx.x * 32;   // over 2048 (h*256+k)
  int c0 = blockIdx.y * 32;    // over 256 couts
  int tx = threadIdx.x & 31, ty = threadIdx.x >> 5;
  int h = kk0 >> 8;
  int k = (kk0 & 255) + ty;
  tile[ty][tx] = W[(size_t)k * HC + h * 256 + c0 + tx] * 0.125f;
  __syncthreads();
  wt2[(size_t)(c0 + ty) * HC + kk0 + tx] = f2b(tile[tx][ty]);
}

// ---------------- fold W against att vectors: wfold[in][h] ----------------
__global__ __launch_bounds__(256) void k_wfold(const float* __restrict__ W,
                                               const float* __restrict__ att_s,
                                               const float* __restrict__ att_d,
                                               float* __restrict__ wsrc,
                                               float* __restrict__ wdst) {
  int in = blockIdx.x;
  int t = threadIdx.x;
  int h = t >> 5;
  int c0 = (t & 31) * 8;
  float ps = 0.f, pd = 0.f;
#pragma unroll
  for (int j = 0; j < 8; ++j) {
    float wv = W[(size_t)in * HC + h * 256 + c0 + j];
    ps += wv * att_s[h * 256 + c0 + j];
    pd += wv * att_d[h * 256 + c0 + j];
  }
#pragma unroll
  for (int o = 16; o >= 1; o >>= 1) {
    ps += __shfl_down(ps, o, 32);
    pd += __shfl_down(pd, o, 32);
  }
  if ((t & 31) == 0) {
    wsrc[in * HH + h] = ps;
    wdst[in * HH + h] = pd;
  }
}

// ---------------- fused: bf16 convert of x + per-node logits + edge histogram ----------------
__global__ __launch_bounds__(256) void k_alog2c(const float* __restrict__ x,
                                                const float* __restrict__ wsrc,
                                                const float* __restrict__ wdst,
                                                const int* __restrict__ dstn,
                                                unsigned short* __restrict__ xb,
                                                float* __restrict__ a_src,
                                                float* __restrict__ a_dst,
                                                int* __restrict__ deg) {
  int gid = blockIdx.x * 256 + threadIdx.x;
  if (gid < EE) atomicAdd(&deg[dstn[gid]], 1);

  const int l = threadIdx.x & 63;
  const int gwave = (blockIdx.x * 256 + threadIdx.x) >> 6;
  const int nwaves = (gridDim.x * 256) >> 6;
  float ws_[4][8], wd_[4][8];
#pragma unroll
  for (int j = 0; j < 4; ++j) {
#pragma unroll
    for (int h = 0; h < 8; ++h) {
      ws_[j][h] = wsrc[(l * 4 + j) * HH + h];
      wd_[j][h] = wdst[(l * 4 + j) * HH + h];
    }
  }
  for (int n = gwave; n < NN; n += nwaves) {
    float4 xv = *(const float4*)(x + (size_t)n * IND + l * 4);
    float xa[4] = {xv.x, xv.y, xv.z, xv.w};
    ushort4 o = make_ushort4(f2b(xv.x), f2b(xv.y), f2b(xv.z), f2b(xv.w));
    *(ushort4*)(xb + (size_t)n * IND + l * 4) = o;
    float as[8] = {}, ad[8] = {};
#pragma unroll
    for (int j = 0; j < 4; ++j)
#pragma unroll
      for (int h = 0; h < 8; ++h) {
        as[h] += xa[j] * ws_[j][h];
        ad[h] += xa[j] * wd_[j][h];
      }
#pragma unroll
    for (int o2 = 32; o2 >= 1; o2 >>= 1) {
#pragma unroll
      for (int h = 0; h < 8; ++h) {
        as[h] += __shfl_down(as[h], o2);
        ad[h] += __shfl_down(ad[h], o2);
      }
    }
    if (l == 0) {
#pragma unroll
      for (int h = 0; h < 8; ++h) {
        a_src[n * HH + h] = as[h];
        a_dst[n * HH + h] = ad[h];
      }
    }
  }
}

// ---------------- CSR build ----------------
__global__ __launch_bounds__(1024) void k_scanA(const int* __restrict__ deg,
                                                int* __restrict__ incl, int* __restrict__ bsum) {
  __shared__ int s[1024];
  int tid = threadIdx.x;
  int i = blockIdx.x * 1024 + tid;
  s[tid] = (i < NN) ? deg[i] : 0;
  __syncthreads();
  for (int o = 1; o < 1024; o <<= 1) {
    int add = (tid >= o) ? s[tid - o] : 0;
    __syncthreads();
    s[tid] += add;
    __syncthreads();
  }
  if (i < NN) incl[i] = s[tid];
  if (tid == 1023) bsum[blockIdx.x] = s[1023];
}

// scanC with fused block-sum prefix (wave 0 scans bsum, <=64 blocks)
__global__ __launch_bounds__(1024) void k_scanC(const int* __restrict__ deg, const int* __restrict__ incl,
                                                const int* __restrict__ bsum, int* __restrict__ row_start,
                                                int* __restrict__ cursor) {
  __shared__ int base_s;
  int tid = threadIdx.x;
  if (tid < 64) {
    int nb = gridDim.x;
    int v = (tid < nb) ? bsum[tid] : 0;
    int p = v;
#pragma unroll
    for (int o = 1; o < 64; o <<= 1) {
      int tt = __shfl_up(p, o, 64);
      if (tid >= o) p += tt;
    }
    if (tid == (int)blockIdx.x) base_s = p - v;   // exclusive prefix for this block
  }
  __syncthreads();
  int i = blockIdx.x * 1024 + tid;
  if (i < NN) {
    int ex = base_s + incl[i] - deg[i];
    row_start[i] = ex;
    cursor[i] = ex;
  }
  if (i == 0) row_start[NN] = EE;
}

__global__ void k_scatter(const int* __restrict__ srcn, const int* __restrict__ dstn,
                          int* __restrict__ cursor, int* __restrict__ csr_src) {
  int e = blockIdx.x * 256 + threadIdx.x;
  if (e < EE) {
    int d = dstn[e];
    int p = atomicAdd(&cursor[d], 1);
    csr_src[p] = srcn[e];
  }
}

// ---------------- fused softmax + aggregate in x-space: SINGLE PASS ----------------
__global__ __launch_bounds__(256) void k_aggxf(const unsigned short* __restrict__ xb,
                                               const float* __restrict__ a_src,
                                               const float* __restrict__ a_dst,
                                               const int* __restrict__ row_start,
                                               const int* __restrict__ csr_src,
                                               unsigned short* __restrict__ y) {
  __shared__ float w_s[4][8][8];    // [wave][edge-in-chunk][head] exp weights
  __shared__ float inv_s[4][8];     // [wave][head] 1/denominator
  const int l = threadIdx.x & 63;
  const int wv = threadIdx.x >> 6;
  const int n = blockIdx.x * 4 + wv;
  if (n >= NN) return;
  const int start = row_start[n];
  const int D = row_start[n + 1] - start;
  unsigned short* yp = y + (size_t)n * HC + l * 4;
  if (D == 0) {
    ushort4 z = make_ushort4(0, 0, 0, 0);
#pragma unroll
    for (int h = 0; h < 8; ++h) *(ushort4*)(yp + h * 256) = z;
    return;
  }
  const int h = l & 7;
  const int e8 = l >> 3;
  const float adst = a_dst[n * HH + h];

  float ssum = 0.f;
  float acc[8][4] = {};
  for (int base = 0; base < D; base += 8) {
    int nch = min(8, D - base);
    int e = base + e8;
    int s = 0;
    float we = 0.f;
    if (e < D) {
      s = csr_src[start + e];
      float xv = a_src[s * HH + h] + adst;
      float lg = (xv > 0.f) ? xv : NEG * xv;
      we = __expf(fminf(lg, 60.f));
      ssum += we;
    }
    w_s[wv][e8][h] = we;   // wave-synchronous LDS
    for (int ee = 0; ee < nch; ++ee) {
      int se = __shfl(s, ee * 8, 64);
      f32x4 a0 = *(const f32x4*)&w_s[wv][ee][0];   // broadcast read
      f32x4 a1 = *(const f32x4*)&w_s[wv][ee][4];
      ushort4 v = *(const ushort4*)(xb + (size_t)se * IND + l * 4);
      float x0 = b2f(v.x), x1 = b2f(v.y), x2 = b2f(v.z), x3 = b2f(v.w);
#pragma unroll
      for (int hh = 0; hh < 8; ++hh) {
        float a = (hh < 4) ? a0[hh] : a1[hh - 4];
        acc[hh][0] += a * x0;
        acc[hh][1] += a * x1;
        acc[hh][2] += a * x2;
        acc[hh][3] += a * x3;
      }
    }
  }
#pragma unroll
  for (int mask = 8; mask < 64; mask <<= 1) ssum += __shfl_xor(ssum, mask, 64);
  if (e8 == 0) inv_s[wv][h] = 1.f / (ssum + EPSV);
  f32x4 i0 = *(const f32x4*)&inv_s[wv][0];
  f32x4 i1 = *(const f32x4*)&inv_s[wv][4];
#pragma unroll
  for (int hh = 0; hh < 8; ++hh) {
    float iv = (hh < 4) ? i0[hh] : i1[hh - 4];
    ushort4 o = make_ushort4(f2b(acc[hh][0] * iv), f2b(acc[hh][1] * iv),
                             f2b(acc[hh][2] * iv), f2b(acc[hh][3] * iv));
    *(ushort4*)(yp + hh * 256) = o;
  }
}

// ---------------- GEMM2: out = y[N][2048] @ wt2^T + bias ----------------
// R10-proven inner loop, BM=192 geometry: grid = 261 ~ 1.02 blocks/CU (near-zero
// tail) and B-restage drops 391 -> 261 MB (total staged 591 -> 461 MB).
// BN=256, BK=64, 8 waves (2M x 4N; wave = 96 rows x 64 cols), single 56KB LDS,
// 2-barrier loop, XOR-swizzled global_load_lds staging.
__global__ __launch_bounds__(512) void k_gemm2(const unsigned short* __restrict__ y,
                                               const unsigned short* __restrict__ wt2,
                                               const float* __restrict__ bias,
                                               float* __restrict__ out) {
  __shared__ unsigned short As[192 * 64];   // 24KB
  __shared__ unsigned short Bs[256 * 64];   // 32KB
  const int t = threadIdx.x;
  const int lane = t & 63;
  const int w = t >> 6;          // 0..7
  const int wr = w >> 2;         // 0..1  (row half: 96 rows)
  const int wc = w & 3;          // 0..3  (col quarter: 64 cols)
  const int l16 = lane & 15;
  const int lq = lane >> 4;
  const int m0 = blockIdx.x * 192;

  f32x4 acc[6][4] = {};

  const int so = t * 16;   // byte offset within an 8KB issue-slice

  for (int ks = 0; ks < 32; ++ks) {
    const int k0 = ks * 64;
#pragma unroll
    for (int i = 0; i < 3; ++i) {       // A: 3 slices (192 rows x 128B)
      int o = i * 8192 + so;
      int row = o >> 7;
      int cg = ((o >> 4) & 7) ^ (row & 7);
      const unsigned short* srcA = y + (size_t)(m0 + row) * HC + k0 + cg * 8;
      __builtin_amdgcn_global_load_lds(
          (const __attribute__((address_space(1))) void*)srcA,
          (__attribute__((address_space(3))) void*)((char*)As + o), 16, 0, 0);
    }
#pragma unroll
    for (int i = 0; i < 4; ++i) {       // B: 4 slices (256 rows x 128B)
      int o = i * 8192 + so;
      int row = o >> 7;
      int cg = ((o >> 4) & 7) ^ (row & 7);
      const unsigned short* srcB = wt2 + (size_t)row * HC + k0 + cg * 8;
      __builtin_amdgcn_global_load_lds(
          (const __attribute__((address_space(1))) void*)srcB,
          (__attribute__((address_space(3))) void*)((char*)Bs + o), 16, 0, 0);
    }
    __syncthreads();
#pragma unroll
    for (int kk = 0; kk < 2; ++kk) {
      short8 af[6], bf[4];
#pragma unroll
      for (int m = 0; m < 6; ++m) {
        int row = wr * 96 + m * 16 + l16;
        int byte = row * 128 + (((kk * 4 + lq) ^ (row & 7)) << 4);
        af[m] = *(const short8*)((const char*)As + byte);
      }
#pragma unroll
      for (int n = 0; n < 4; ++n) {
        int row = wc * 64 + n * 16 + l16;
        int byte = row * 128 + (((kk * 4 + lq) ^ (row & 7)) << 4);
        bf[n] = *(const short8*)((const char*)Bs + byte);
      }
      __builtin_amdgcn_s_setprio(1);
#pragma unroll
      for (int m = 0; m < 6; ++m)
#pragma unroll
        for (int n = 0; n < 4; ++n)
          acc[m][n] = __builtin_amdgcn_mfma_f32_16x16x32_bf16(af[m], bf[n], acc[m][n], 0, 0, 0);
      __builtin_amdgcn_s_setprio(0);
    }
    __syncthreads();
  }

  const int r0 = lq * 4;
#pragma unroll
  for (int n = 0; n < 4; ++n) {
    int gcol = wc * 64 + n * 16 + l16;
    float bv = bias[gcol];
#pragma unroll
    for (int m = 0; m < 6; ++m) {
#pragma unroll
      for (int r = 0; r < 4; ++r) {
        int grow = m0 + wr * 96 + m * 16 + r0 + r;
        if (grow < NN) out[(size_t)grow * CC + gcol] = acc[m][n][r] + bv;
      }
    }
  }
}

// ---------------- launch ----------------
extern "C" void kernel_launch(void* const* d_in, const int* in_sizes, int n_in,
                              void* d_out, int out_size, void* d_ws, size_t ws_size,
                              hipStream_t stream) {
  (void)in_sizes; (void)n_in; (void)out_size; (void)ws_size;
  const float* x = (const float*)d_in[0];
  const int* ei = (const int*)d_in[1];
  const float* W = (const float*)d_in[2];
  const float* att_s = (const float*)d_in[3];
  const float* att_d = (const float*)d_in[4];
  const float* bias = (const float*)d_in[5];
  float* out = (float*)d_out;
  const int* srcp = ei;
  const int* dstp = ei + EE;

  char* ws = (char*)d_ws;
  size_t off = 0;
  auto alloc = [&](size_t bytes) {
    void* p = ws + off;
    off = (off + bytes + 255) & ~(size_t)255;
    return p;
  };
  unsigned short* y = (unsigned short*)alloc((size_t)NN * HC * 2);
  unsigned short* xb = (unsigned short*)alloc((size_t)NN * IND * 2);  // also OOB pad for y rows >= NN
  unsigned short* wt2 = (unsigned short*)alloc((size_t)HC * IND * 2);
  float* wsrc = (float*)alloc((size_t)IND * HH * 4);
  float* wdst = (float*)alloc((size_t)IND * HH * 4);
  float* a_src = (float*)alloc((size_t)NN * HH * 4);
  float* a_dst = (float*)alloc((size_t)NN * HH * 4);
  int* deg = (int*)alloc((size_t)NN * 4);
  int* incl = (int*)alloc((size_t)NN * 4);
  int* row_start = (int*)alloc((size_t)(NN + 1) * 4);
  int* cursor = (int*)alloc((size_t)NN * 4);
  int* csr_src = (int*)alloc((size_t)EE * 4);
  int* bsum = (int*)alloc(256);

  hipMemsetAsync(deg, 0, (size_t)NN * 4, stream);

  k_wt2<<<dim3(HC / 32, CC / 32), 1024, 0, stream>>>(W, wt2);
  k_wfold<<<IND, 256, 0, stream>>>(W, att_s, att_d, wsrc, wdst);
  k_alog2c<<<832, 256, 0, stream>>>(x, wsrc, wdst, dstp, xb, a_src, a_dst, deg);
  int nb = (NN + 1023) / 1024;
  k_scanA<<<nb, 1024, 0, stream>>>(deg, incl, bsum);
  k_scanC<<<nb, 1024, 0, stream>>>(deg, incl, bsum, row_start, cursor);
  k_scatter<<<(EE + 255) / 256, 256, 0, stream>>>(srcp, dstp, cursor, csr_src);
  k_aggxf<<<(NN + 3) / 4, 256, 0, stream>>>(xb, a_src, a_dst, row_start, csr_src, y);
  k_gemm2<<<(NN + 191) / 192, 512, 0, stream>>>(y, wt2, bias, out);
}

// Round 18
// 242.454 us; speedup vs baseline: 1.3215x; 1.3181x over previous
//
#include <hip/hip_runtime.h>
#include <hip/hip_bf16.h>

#define NN 50000
#define EE 200000
#define HH 8
#define CC 256
#define IND 256
#define HC 2048
#define NEG 0.2f
#define EPSV 1e-16f

typedef __attribute__((ext_vector_type(8))) short short8;
typedef __attribute__((ext_vector_type(4))) float f32x4;

__device__ __forceinline__ float b2f(unsigned short u) {
  return __uint_as_float(((unsigned)u) << 16);
}
__device__ __forceinline__ unsigned short f2b(float f) {
  unsigned u = __float_as_uint(f);
  unsigned r = (u + 0x7FFFu + ((u >> 16) & 1u)) >> 16;
  return (unsigned short)r;
}

// ---------------- build Wstack^T: wt2[cout][kk] = W[kk&255][(kk>>8)*256+cout]*0.125 ----------------
__global__ __launch_bounds__(1024) void k_wt2(const float* __restrict__ W,
                                              unsigned short* __restrict__ wt2) {
  __shared__ float tile[32][33];
  int kk0 = blockIdx.x * 32;   // over 2048 (h*256+k)
  int c0 = blockIdx.y * 32;    // over 256 couts
  int tx = threadIdx.x & 31, ty = threadIdx.x >> 5;
  int h = kk0 >> 8;
  int k = (kk0 & 255) + ty;
  tile[ty][tx] = W[(size_t)k * HC + h * 256 + c0 + tx] * 0.125f;
  __syncthreads();
  wt2[(size_t)(c0 + ty) * HC + kk0 + tx] = f2b(tile[tx][ty]);
}

// ---------------- fold W against att vectors: wfold[in][h] ----------------
__global__ __launch_bounds__(256) void k_wfold(const float* __restrict__ W,
                                               const float* __restrict__ att_s,
                                               const float* __restrict__ att_d,
                                               float* __restrict__ wsrc,
                                               float* __restrict__ wdst) {
  int in = blockIdx.x;
  int t = threadIdx.x;
  int h = t >> 5;
  int c0 = (t & 31) * 8;
  float ps = 0.f, pd = 0.f;
#pragma unroll
  for (int j = 0; j < 8; ++j) {
    float wv = W[(size_t)in * HC + h * 256 + c0 + j];
    ps += wv * att_s[h * 256 + c0 + j];
    pd += wv * att_d[h * 256 + c0 + j];
  }
#pragma unroll
  for (int o = 16; o >= 1; o >>= 1) {
    ps += __shfl_down(ps, o, 32);
    pd += __shfl_down(pd, o, 32);
  }
  if ((t & 31) == 0) {
    wsrc[in * HH + h] = ps;
    wdst[in * HH + h] = pd;
  }
}

// ---------------- fused: bf16 convert of x + per-node logits + edge histogram ----------------
__global__ __launch_bounds__(256) void k_alog2c(const float* __restrict__ x,
                                                const float* __restrict__ wsrc,
                                                const float* __restrict__ wdst,
                                                const int* __restrict__ dstn,
                                                unsigned short* __restrict__ xb,
                                                float* __restrict__ a_src,
                                                float* __restrict__ a_dst,
                                                int* __restrict__ deg) {
  int gid = blockIdx.x * 256 + threadIdx.x;
  if (gid < EE) atomicAdd(&deg[dstn[gid]], 1);

  const int l = threadIdx.x & 63;
  const int gwave = (blockIdx.x * 256 + threadIdx.x) >> 6;
  const int nwaves = (gridDim.x * 256) >> 6;
  float ws_[4][8], wd_[4][8];
#pragma unroll
  for (int j = 0; j < 4; ++j) {
#pragma unroll
    for (int h = 0; h < 8; ++h) {
      ws_[j][h] = wsrc[(l * 4 + j) * HH + h];
      wd_[j][h] = wdst[(l * 4 + j) * HH + h];
    }
  }
  for (int n = gwave; n < NN; n += nwaves) {
    float4 xv = *(const float4*)(x + (size_t)n * IND + l * 4);
    float xa[4] = {xv.x, xv.y, xv.z, xv.w};
    ushort4 o = make_ushort4(f2b(xv.x), f2b(xv.y), f2b(xv.z), f2b(xv.w));
    *(ushort4*)(xb + (size_t)n * IND + l * 4) = o;
    float as[8] = {}, ad[8] = {};
#pragma unroll
    for (int j = 0; j < 4; ++j)
#pragma unroll
      for (int h = 0; h < 8; ++h) {
        as[h] += xa[j] * ws_[j][h];
        ad[h] += xa[j] * wd_[j][h];
      }
#pragma unroll
    for (int o2 = 32; o2 >= 1; o2 >>= 1) {
#pragma unroll
      for (int h = 0; h < 8; ++h) {
        as[h] += __shfl_down(as[h], o2);
        ad[h] += __shfl_down(ad[h], o2);
      }
    }
    if (l == 0) {
#pragma unroll
      for (int h = 0; h < 8; ++h) {
        a_src[n * HH + h] = as[h];
        a_dst[n * HH + h] = ad[h];
      }
    }
  }
}

// ---------------- CSR build ----------------
__global__ __launch_bounds__(1024) void k_scanA(const int* __restrict__ deg,
                                                int* __restrict__ incl, int* __restrict__ bsum) {
  __shared__ int s[1024];
  int tid = threadIdx.x;
  int i = blockIdx.x * 1024 + tid;
  s[tid] = (i < NN) ? deg[i] : 0;
  __syncthreads();
  for (int o = 1; o < 1024; o <<= 1) {
    int add = (tid >= o) ? s[tid - o] : 0;
    __syncthreads();
    s[tid] += add;
    __syncthreads();
  }
  if (i < NN) incl[i] = s[tid];
  if (tid == 1023) bsum[blockIdx.x] = s[1023];
}

// scanC with fused block-sum prefix (wave 0 scans bsum, <=64 blocks)
__global__ __launch_bounds__(1024) void k_scanC(const int* __restrict__ deg, const int* __restrict__ incl,
                                                const int* __restrict__ bsum, int* __restrict__ row_start,
                                                int* __restrict__ cursor) {
  __shared__ int base_s;
  int tid = threadIdx.x;
  if (tid < 64) {
    int nb = gridDim.x;
    int v = (tid < nb) ? bsum[tid] : 0;
    int p = v;
#pragma unroll
    for (int o = 1; o < 64; o <<= 1) {
      int tt = __shfl_up(p, o, 64);
      if (tid >= o) p += tt;
    }
    if (tid == (int)blockIdx.x) base_s = p - v;   // exclusive prefix for this block
  }
  __syncthreads();
  int i = blockIdx.x * 1024 + tid;
  if (i < NN) {
    int ex = base_s + incl[i] - deg[i];
    row_start[i] = ex;
    cursor[i] = ex;
  }
  if (i == 0) row_start[NN] = EE;
}

__global__ void k_scatter(const int* __restrict__ srcn, const int* __restrict__ dstn,
                          int* __restrict__ cursor, int* __restrict__ csr_src) {
  int e = blockIdx.x * 256 + threadIdx.x;
  if (e < EE) {
    int d = dstn[e];
    int p = atomicAdd(&cursor[d], 1);
    csr_src[p] = srcn[e];
  }
}

// ---------------- fused softmax + aggregate in x-space: SINGLE PASS, 2 nodes/wave ----------------
// 32 lanes per node; lane owns 8 contiguous channels (16B loads/stores).
// Weight lanes: (e4 = l32>>3 in 0..3, h = l32&7); chunk = 4 edges.
__global__ __launch_bounds__(256) void k_aggxf(const unsigned short* __restrict__ xb,
                                               const float* __restrict__ a_src,
                                               const float* __restrict__ a_dst,
                                               const int* __restrict__ row_start,
                                               const int* __restrict__ csr_src,
                                               unsigned short* __restrict__ y) {
  __shared__ float w_s[4][2][4][8];   // [wave][half][edge][head] exp weights
  __shared__ float inv_s[4][2][8];    // [wave][half][head]
  const int lane = threadIdx.x & 63;
  const int wv = threadIdx.x >> 6;
  const int half = lane >> 5;
  const int l32 = lane & 31;
  const int n = blockIdx.x * 8 + wv * 2 + half;
  if (n >= NN) return;
  const int start = row_start[n];
  const int D = row_start[n + 1] - start;
  unsigned short* yp = y + (size_t)n * HC + l32 * 8;
  if (D == 0) {
    short8 z = {};
#pragma unroll
    for (int h = 0; h < 8; ++h) *(short8*)(yp + h * 256) = z;
    return;
  }
  const int h = l32 & 7;
  const int e4 = l32 >> 3;
  const float adst = a_dst[n * HH + h];

  float ssum = 0.f;
  float acc[8][8] = {};   // [head][ch]
  for (int base = 0; base < D; base += 4) {
    int nch = min(4, D - base);
    int e = base + e4;
    int s = 0;
    float we = 0.f;
    if (e < D) {
      s = csr_src[start + e];
      float xv = a_src[s * HH + h] + adst;
      float lg = (xv > 0.f) ? xv : NEG * xv;
      we = __expf(fminf(lg, 60.f));
      ssum += we;
    }
    w_s[wv][half][e4][h] = we;   // wave-synchronous LDS
    for (int ee = 0; ee < nch; ++ee) {
      int se = __shfl(s, ee * 8, 32);
      f32x4 a0 = *(const f32x4*)&w_s[wv][half][ee][0];   // broadcast read
      f32x4 a1 = *(const f32x4*)&w_s[wv][half][ee][4];
      short8 v = *(const short8*)(xb + (size_t)se * IND + l32 * 8);
      float xc[8];
#pragma unroll
      for (int j = 0; j < 8; ++j) xc[j] = b2f((unsigned short)v[j]);
#pragma unroll
      for (int hh = 0; hh < 8; ++hh) {
        float a = (hh < 4) ? a0[hh] : a1[hh - 4];
#pragma unroll
        for (int j = 0; j < 8; ++j) acc[hh][j] += a * xc[j];
      }
    }
  }
  // reduce ssum across the 4 e4-groups (width-32)
  ssum += __shfl_xor(ssum, 8, 32);
  ssum += __shfl_xor(ssum, 16, 32);
  if (e4 == 0) inv_s[wv][half][h] = 1.f / (ssum + EPSV);
  f32x4 i0 = *(const f32x4*)&inv_s[wv][half][0];
  f32x4 i1 = *(const f32x4*)&inv_s[wv][half][4];
#pragma unroll
  for (int hh = 0; hh < 8; ++hh) {
    float iv = (hh < 4) ? i0[hh] : i1[hh - 4];
    short8 o;
#pragma unroll
    for (int j = 0; j < 8; ++j) o[j] = (short)f2b(acc[hh][j] * iv);
    *(short8*)(yp + hh * 256) = o;
  }
}

// ---------------- GEMM2: out = y[N][2048] @ wt2^T + bias (R10-proven, CONVERGED) ----------------
// BM=128, BN=256, BK=64, 8 waves, SINGLE-buffer 48KB LDS, 2-barrier loop.
// Empirical optimum of 9 structures tried (rounds 5-17); do not touch.
__global__ __launch_bounds__(512) void k_gemm2(const unsigned short* __restrict__ y,
                                               const unsigned short* __restrict__ wt2,
                                               const float* __restrict__ bias,
                                               float* __restrict__ out) {
  __shared__ unsigned short As[128 * 64];   // 16KB
  __shared__ unsigned short Bs[256 * 64];   // 32KB
  const int t = threadIdx.x;
  const int lane = t & 63;
  const int w = t >> 6;          // 0..7
  const int wr = w >> 2;         // 0..1  (row half)
  const int wc = w & 3;          // 0..3  (col quarter)
  const int l16 = lane & 15;
  const int lq = lane >> 4;
  const int m0 = blockIdx.x * 128;

  f32x4 acc[4][4] = {};

  const int so = t * 16;   // byte offset within an 8KB issue-slice

  for (int ks = 0; ks < 32; ++ks) {
    const int k0 = ks * 64;
#pragma unroll
    for (int i = 0; i < 2; ++i) {
      int o = i * 8192 + so;
      int row = o >> 7;
      int cg = ((o >> 4) & 7) ^ (row & 7);
      const unsigned short* srcA = y + (size_t)(m0 + row) * HC + k0 + cg * 8;
      __builtin_amdgcn_global_load_lds(
          (const __attribute__((address_space(1))) void*)srcA,
          (__attribute__((address_space(3))) void*)((char*)As + o), 16, 0, 0);
    }
#pragma unroll
    for (int i = 0; i < 4; ++i) {
      int o = i * 8192 + so;
      int row = o >> 7;
      int cg = ((o >> 4) & 7) ^ (row & 7);
      const unsigned short* srcB = wt2 + (size_t)row * HC + k0 + cg * 8;
      __builtin_amdgcn_global_load_lds(
          (const __attribute__((address_space(1))) void*)srcB,
          (__attribute__((address_space(3))) void*)((char*)Bs + o), 16, 0, 0);
    }
    __syncthreads();
#pragma unroll
    for (int kk = 0; kk < 2; ++kk) {
      short8 af[4], bf[4];
#pragma unroll
      for (int m = 0; m < 4; ++m) {
        int row = wr * 64 + m * 16 + l16;
        int byte = row * 128 + (((kk * 4 + lq) ^ (row & 7)) << 4);
        af[m] = *(const short8*)((const char*)As + byte);
      }
#pragma unroll
      for (int n = 0; n < 4; ++n) {
        int row = wc * 64 + n * 16 + l16;
        int byte = row * 128 + (((kk * 4 + lq) ^ (row & 7)) << 4);
        bf[n] = *(const short8*)((const char*)Bs + byte);
      }
      __builtin_amdgcn_s_setprio(1);
#pragma unroll
      for (int m = 0; m < 4; ++m)
#pragma unroll
        for (int n = 0; n < 4; ++n)
          acc[m][n] = __builtin_amdgcn_mfma_f32_16x16x32_bf16(af[m], bf[n], acc[m][n], 0, 0, 0);
      __builtin_amdgcn_s_setprio(0);
    }
    __syncthreads();
  }

  const int r0 = lq * 4;
#pragma unroll
  for (int n = 0; n < 4; ++n) {
    int gcol = wc * 64 + n * 16 + l16;
    float bv = bias[gcol];
#pragma unroll
    for (int m = 0; m < 4; ++m) {
#pragma unroll
      for (int r = 0; r < 4; ++r) {
        int grow = m0 + wr * 64 + m * 16 + r0 + r;
        if (grow < NN) out[(size_t)grow * CC + gcol] = acc[m][n][r] + bv;
      }
    }
  }
}

// ---------------- launch ----------------
extern "C" void kernel_launch(void* const* d_in, const int* in_sizes, int n_in,
                              void* d_out, int out_size, void* d_ws, size_t ws_size,
                              hipStream_t stream) {
  (void)in_sizes; (void)n_in; (void)out_size; (void)ws_size;
  const float* x = (const float*)d_in[0];
  const int* ei = (const int*)d_in[1];
  const float* W = (const float*)d_in[2];
  const float* att_s = (const float*)d_in[3];
  const float* att_d = (const float*)d_in[4];
  const float* bias = (const float*)d_in[5];
  float* out = (float*)d_out;
  const int* srcp = ei;
  const int* dstp = ei + EE;

  char* ws = (char*)d_ws;
  size_t off = 0;
  auto alloc = [&](size_t bytes) {
    void* p = ws + off;
    off = (off + bytes + 255) & ~(size_t)255;
    return p;
  };
  unsigned short* y = (unsigned short*)alloc((size_t)NN * HC * 2);
  unsigned short* xb = (unsigned short*)alloc((size_t)NN * IND * 2);  // also OOB pad for y rows >= NN
  unsigned short* wt2 = (unsigned short*)alloc((size_t)HC * IND * 2);
  float* wsrc = (float*)alloc((size_t)IND * HH * 4);
  float* wdst = (float*)alloc((size_t)IND * HH * 4);
  float* a_src = (float*)alloc((size_t)NN * HH * 4);
  float* a_dst = (float*)alloc((size_t)NN * HH * 4);
  int* deg = (int*)alloc((size_t)NN * 4);
  int* incl = (int*)alloc((size_t)NN * 4);
  int* row_start = (int*)alloc((size_t)(NN + 1) * 4);
  int* cursor = (int*)alloc((size_t)NN * 4);
  int* csr_src = (int*)alloc((size_t)EE * 4);
  int* bsum = (int*)alloc(256);

  hipMemsetAsync(deg, 0, (size_t)NN * 4, stream);

  k_wt2<<<dim3(HC / 32, CC / 32), 1024, 0, stream>>>(W, wt2);
  k_wfold<<<IND, 256, 0, stream>>>(W, att_s, att_d, wsrc, wdst);
  k_alog2c<<<832, 256, 0, stream>>>(x, wsrc, wdst, dstp, xb, a_src, a_dst, deg);
  int nb = (NN + 1023) / 1024;
  k_scanA<<<nb, 1024, 0, stream>>>(deg, incl, bsum);
  k_scanC<<<nb, 1024, 0, stream>>>(deg, incl, bsum, row_start, cursor);
  k_scatter<<<(EE + 255) / 256, 256, 0, stream>>>(srcp, dstp, cursor, csr_src);
  k_aggxf<<<(NN + 7) / 8, 256, 0, stream>>>(xb, a_src, a_dst, row_start, csr_src, y);
  k_gemm2<<<(NN + 127) / 128, 512, 0, stream>>>(y, wt2, bias, out);
}